// Round 3
// baseline (435.636 us; speedup 1.0000x reference)
//
#include <hip/hip_runtime.h>

// SepConv: out[b,c,i,j] = sum_{u,v} img[b,c,i+u,j+v] * vert[b,u,i,j] * hori[b,v,i,j]
// B=8, C=3, W=H=512, K=13, Wo=Ho=500.
//
// R9: producer-consumer wave specialization. Evidence trail:
//  - R6 (stage+drain+compute per block): 114us, 2.07 TB/s, occ 28% -- the
//    vmcnt(0)+barrier drain convoys all 6 waves; in-flight bytes/CU ~3KB
//    vs ~9KB needed (6.3TB/s x 375ns / 256 CU).
//  - R8 (TLP + rotating scalar prefetch): 194us, 1.2 TB/s -- rotation chain
//    serialized iterations; latency exposed 13x per row.
//  - Counted-vmcnt single-stream doesn't work here: consumer img loads are
//    issued AFTER staged DMA, and vmcnt retires in order, so waiting for an
//    img row force-drains the next weight stage mid-compute.
// Fix: vmcnt is PER-WAVE. One dedicated producer wave keeps ~51
// global_load_lds (52KB) in flight continuously and drains with its own
// vmcnt(0); consumers never touch DMA counters. Handoff = LDS generation
// flags (workgroup acquire/release atomics). No __syncthreads in the loop.
// Block = 6 consumer waves (R6's float4 compute, VGPR 52) + 1 producer
// wave. RPB=4 rows/block, double-buffered weights (2x52KB -> 1 block/CU).
// Steady state: producer stages row r+1 (~2.1us at per-CU BW share) while
// consumers compute row r (~1.2-2us) -> DMA/BW-bound by construction.
// Occupancy ~20% is BY DESIGN (outstanding bytes come from the producer,
// not TLP).

#define KK 13
#define NB 8
#define NC 3
#define IW 512
#define IH 512
#define WO 500
#define HO 500
#define QROW 125              // float4 quads per 500-col row
#define RPB 4                 // output rows per block
#define NCONS 384             // consumer threads: 128 j-quads x 3 channels
#define NT (NCONS + 64)       // + 1 producer wave
#define NQ4 (2 * KK * QROW)   // 3250 quads per row (vert then hori)
#define NQPAD 3264            // 51 * 64: uniform 51 loads per producer lane

typedef __attribute__((address_space(1))) const void g_void;
typedef __attribute__((address_space(3))) void l_void;

__global__ __launch_bounds__(NT) void sepconv_kernel(
    const float* __restrict__ img,
    const float* __restrict__ hori,
    const float* __restrict__ vert,
    float* __restrict__ out)
{
    __shared__ float4 s_w[2][NQPAD];   // [buf][vert 0..1624 | hori 1625..3249 | pad]
    __shared__ int ready_gen[2];       // row staged into buf, -1 = none
    __shared__ int done_cnt[RPB];      // consumer waves finished row r

    const int tid = threadIdx.x;
    const int b  = blockIdx.y;
    const int i0 = blockIdx.x * RPB;

    if (tid == 0) {
        ready_gen[0] = -1; ready_gen[1] = -1;
        #pragma unroll
        for (int r = 0; r < RPB; ++r) done_cnt[r] = 0;
    }
    __syncthreads();   // only barrier in the kernel: flag init visibility

    const size_t khw = (size_t)WO * HO;      // 250000
    const size_t rs4 = khw / 4;              // 62500 float4 between k-slices

    if (tid >= NCONS) {
        // ---------------- producer wave ----------------
        const int lane = tid - NCONS;
        const float4* vb0 = (const float4*)(vert + (size_t)b * KK * khw);
        const float4* hb0 = (const float4*)(hori + (size_t)b * KK * khw);
        for (int r = 0; r < RPB; ++r) {
            if (r >= 2) {
                // buf[r&1] holds row r-2; wait until all 6 consumer waves
                // consumed it before overwriting.
                while (__hip_atomic_load(&done_cnt[r - 2], __ATOMIC_ACQUIRE,
                                         __HIP_MEMORY_SCOPE_WORKGROUP) < 6)
                    __builtin_amdgcn_s_sleep(1);
            }
            const int bi = r & 1;
            const float4* vb = vb0 + (size_t)(i0 + r) * QROW;
            const float4* hb = hb0 + (size_t)(i0 + r) * QROW;
            #pragma unroll
            for (int s = 0; s < NQPAD / 64; ++s) {
                const int f = s * 64 + lane;
                // branchless src select (single DMA call site, no exec
                // divergence; dest stays wave-uniform base + lane*16)
                int g = (f < KK * QROW) ? f : f - KK * QROW;
                const float4* base = (f < KK * QROW) ? vb : hb;
                if (f >= NQ4) { g = 0; base = vb; }   // pad slots: dummy src
                const unsigned u = (unsigned)g / QROW;
                const unsigned q = (unsigned)g - u * QROW;
                __builtin_amdgcn_global_load_lds(
                    (g_void*)(base + (size_t)u * rs4 + q),
                    (l_void*)&s_w[bi][f], 16, 0, 0);
            }
            // drain THIS WAVE's DMA only, then publish.
            asm volatile("s_waitcnt vmcnt(0)" ::: "memory");
            __hip_atomic_store(&ready_gen[bi], r, __ATOMIC_RELEASE,
                               __HIP_MEMORY_SCOPE_WORKGROUP);
        }
        return;
    }

    // ---------------- consumer waves ----------------
    const int tj = tid & 127;       // j-quad
    const int c  = tid >> 7;        // channel
    const bool active = (tj < QROW);
    const int j0 = tj * 4;

    for (int r = 0; r < RPB; ++r) {
        const int bi = r & 1;
        while (__hip_atomic_load(&ready_gen[bi], __ATOMIC_ACQUIRE,
                                 __HIP_MEMORY_SCOPE_WORKGROUP) < r)
            __builtin_amdgcn_s_sleep(1);

        float tmp[4][KK];
        #pragma unroll
        for (int jq = 0; jq < 4; ++jq)
            #pragma unroll
            for (int v = 0; v < KK; ++v)
                tmp[jq][v] = 0.0f;

        if (active) {
            const int i = i0 + r;
            const float* ibase = img + (((size_t)(b * NC + c) * IW) + i) * IH + j0;

            // img pipeline prologue: row u = 0
            float4 c0 = *(const float4*)(ibase + 0);
            float4 c1 = *(const float4*)(ibase + 4);
            float4 c2 = *(const float4*)(ibase + 8);
            float4 c3 = *(const float4*)(ibase + 12);

            #pragma unroll
            for (int u = 0; u < KK; ++u) {
                // issue next img row before this iteration's FMAs
                float4 n0, n1, n2, n3;
                if (u < KK - 1) {
                    const float* rp = ibase + (size_t)(u + 1) * IH;
                    n0 = *(const float4*)(rp + 0);
                    n1 = *(const float4*)(rp + 4);
                    n2 = *(const float4*)(rp + 8);
                    n3 = *(const float4*)(rp + 12);
                }

                const float4 vt = s_w[bi][u * QROW + tj];   // ds_read_b128

                float row[16];
                row[0]  = c0.x; row[1]  = c0.y; row[2]  = c0.z; row[3]  = c0.w;
                row[4]  = c1.x; row[5]  = c1.y; row[6]  = c1.z; row[7]  = c1.w;
                row[8]  = c2.x; row[9]  = c2.y; row[10] = c2.z; row[11] = c2.w;
                row[12] = c3.x; row[13] = c3.y; row[14] = c3.z; row[15] = c3.w;

                #pragma unroll
                for (int v = 0; v < KK; ++v) {
                    tmp[0][v] += row[0 + v] * vt.x;
                    tmp[1][v] += row[1 + v] * vt.y;
                    tmp[2][v] += row[2 + v] * vt.z;
                    tmp[3][v] += row[3 + v] * vt.w;
                }

                if (u < KK - 1) {
                    c0 = n0; c1 = n1; c2 = n2; c3 = n3;
                }
            }

            // epilogue: fold hori from LDS
            float4 o = make_float4(0.f, 0.f, 0.f, 0.f);
            #pragma unroll
            for (int v = 0; v < KK; ++v) {
                const float4 hv = s_w[bi][KK * QROW + v * QROW + tj];
                o.x += tmp[0][v] * hv.x;
                o.y += tmp[1][v] * hv.y;
                o.z += tmp[2][v] * hv.z;
                o.w += tmp[3][v] * hv.w;
            }

            float* op = out + (((size_t)(b * NC + c) * WO) + (size_t)(i0 + r)) * HO + j0;
            *(float4*)op = o;
        }

        // one release-add per wave: LDS reads of buf[bi] are done.
        if ((tid & 63) == 0)
            __hip_atomic_fetch_add(&done_cnt[r], 1, __ATOMIC_RELEASE,
                                   __HIP_MEMORY_SCOPE_WORKGROUP);
    }
}

extern "C" void kernel_launch(void* const* d_in, const int* in_sizes, int n_in,
                              void* d_out, int out_size, void* d_ws, size_t ws_size,
                              hipStream_t stream) {
    const float* img  = (const float*)d_in[0];
    const float* hori = (const float*)d_in[1];
    const float* vert = (const float*)d_in[2];
    float* out = (float*)d_out;

    dim3 block(NT, 1, 1);         // 384 consumer + 64 producer threads
    dim3 grid(WO / RPB, NB, 1);   // 125 row-groups x 8 batches
    hipLaunchKernelGGL(sepconv_kernel, grid, block, 0, stream, img, hori, vert, out);
}

// Round 4
// 309.169 us; speedup vs baseline: 1.4091x; 1.4091x over previous
//
#include <hip/hip_runtime.h>

// SepConv: out[b,c,i,j] = sum_{u,v} img[b,c,i+u,j+v] * vert[b,u,i,j] * hori[b,v,i,j]
// B=8, C=3, W=H=512, K=13, Wo=Ho=500.
//
// R10: no LDS, no DMA, no barriers. Evidence trail:
//  - Compulsory traffic 257MB -> ~40us floor; VALU floor ~28us. R6 = 114.7us.
//  - R6's convoy: all 6 waves stall on vmcnt(0)+barrier draining 52KB of
//    cold-HBM weights before any compute; in-flight bytes/CU ~3KB vs ~9KB
//    needed.
//  - R7/R9 tried to hide the drain and both died to register spills
//    (WRITE_SIZE 1.45GB / 0.45GB vs 24MB output).
//  - LDS staging buys nothing: weights are read-once; the only reuse is
//    the 3 channel-waves reading identical addresses simultaneously -> L2
//    broadcast handles that with zero HBM cost (guide: don't stage what
//    cache-fits).
// Structure: swap reduction order to
//     out = sum_u vert[u] * (sum_v img[u, j+v] * hori[v])
// so hori (13 float4 = 52 regs) stays register-resident for the whole
// u-loop and the accumulator is just o[4] -- kills tmp[4][13] AND the LDS.
// vert: depth-2 rotating prefetch; img rows: depth-1 rotation (both proven
// un-sinkable patterns from R5/R6). 192-thread blocks (3 waves), ~5
// blocks/CU by VGPR -> ~15 waves continuously issuing independent loads;
// no sync point anywhere, so outstanding bytes come from occupancy instead
// of a drain-then-compute burst.

#define KK 13
#define NB 8
#define NC 3
#define IW 512
#define IH 512
#define WO 500
#define HO 500
#define QROW 125              // float4 quads per 500-col row
#define TJX 64                // j-quads per block
#define NT (TJX * NC)         // 192 threads = 3 waves

__global__ __launch_bounds__(NT) void sepconv_kernel(
    const float* __restrict__ img,
    const float* __restrict__ hori,
    const float* __restrict__ vert,
    float* __restrict__ out)
{
    const int tj = blockIdx.x * TJX + threadIdx.x;   // j-quad 0..127
    const int c  = threadIdx.y;                      // channel
    const int i  = blockIdx.y;                       // output row
    const int b  = blockIdx.z;                       // batch

    if (tj >= QROW) return;                          // tail lanes of group 1
    const int j0 = tj * 4;

    const size_t khw = (size_t)WO * HO;              // 250000
    const size_t rs4 = khw / 4;                      // 62500 float4 between k-slices

    const float4* hb = (const float4*)(hori + (size_t)b * KK * khw + (size_t)i * HO) + tj;
    const float4* vb = (const float4*)(vert + (size_t)b * KK * khw + (size_t)i * HO) + tj;
    const float*  ibase = img + (((size_t)(b * NC + c) * IW) + i) * IH + j0;

    // ---- hori: 13 independent coalesced float4 loads, register-resident.
    // Issued back-to-back up front; latency hides under the img/vert
    // prologue waits + other waves.
    float4 h[KK];
    #pragma unroll
    for (int v = 0; v < KK; ++v)
        h[v] = hb[(size_t)v * rs4];

    // ---- prologue: img row u=0, vert rows u=0,1 ----
    float4 vt_c = vb[0];
    float4 vt_n = vb[rs4];
    float4 c0 = *(const float4*)(ibase + 0);
    float4 c1 = *(const float4*)(ibase + 4);
    float4 c2 = *(const float4*)(ibase + 8);
    float4 c3 = *(const float4*)(ibase + 12);

    float4 o = make_float4(0.f, 0.f, 0.f, 0.f);

    #pragma unroll
    for (int u = 0; u < KK; ++u) {
        // issue next img row + vert row u+2 before this iteration's FMAs
        float4 n0, n1, n2, n3, vt_nn;
        if (u < KK - 1) {
            const float* rp = ibase + (size_t)(u + 1) * IH;
            n0 = *(const float4*)(rp + 0);
            n1 = *(const float4*)(rp + 4);
            n2 = *(const float4*)(rp + 8);
            n3 = *(const float4*)(rp + 12);
        }
        if (u < KK - 2) {
            vt_nn = vb[(size_t)(u + 2) * rs4];
        }

        float row[16];
        row[0]  = c0.x; row[1]  = c0.y; row[2]  = c0.z; row[3]  = c0.w;
        row[4]  = c1.x; row[5]  = c1.y; row[6]  = c1.z; row[7]  = c1.w;
        row[8]  = c2.x; row[9]  = c2.y; row[10] = c2.z; row[11] = c2.w;
        row[12] = c3.x; row[13] = c3.y; row[14] = c3.z; row[15] = c3.w;

        // s[jq] = sum_v img[u, j0+jq+v] * hori[v][j0+jq]
        float s0 = 0.f, s1 = 0.f, s2 = 0.f, s3 = 0.f;
        #pragma unroll
        for (int v = 0; v < KK; ++v) {
            s0 += row[v + 0] * h[v].x;
            s1 += row[v + 1] * h[v].y;
            s2 += row[v + 2] * h[v].z;
            s3 += row[v + 3] * h[v].w;
        }
        o.x += vt_c.x * s0;
        o.y += vt_c.y * s1;
        o.z += vt_c.z * s2;
        o.w += vt_c.w * s3;

        if (u < KK - 1) {
            c0 = n0; c1 = n1; c2 = n2; c3 = n3;
        }
        vt_c = vt_n;
        vt_n = vt_nn;
    }

    float* op = out + (((size_t)(b * NC + c) * WO) + i) * HO + j0;
    *(float4*)op = o;
}

extern "C" void kernel_launch(void* const* d_in, const int* in_sizes, int n_in,
                              void* d_out, int out_size, void* d_ws, size_t ws_size,
                              hipStream_t stream) {
    const float* img  = (const float*)d_in[0];
    const float* hori = (const float*)d_in[1];
    const float* vert = (const float*)d_in[2];
    float* out = (float*)d_out;

    dim3 block(TJX, NC, 1);       // x = j-quads, y = channel
    dim3 grid(2, WO, NB);         // x = quad-group, y = row i, z = batch
    hipLaunchKernelGGL(sepconv_kernel, grid, block, 0, stream, img, hori, vert, out);
}

// Round 5
// 285.962 us; speedup vs baseline: 1.5234x; 1.0812x over previous
//
#include <hip/hip_runtime.h>

// SepConv: out[b,c,i,j] = sum_{u,v} img[b,c,i+u,j+v] * vert[b,u,i,j] * hori[b,v,i,j]
// B=8, C=3, W=H=512, K=13, Wo=Ho=500.
//
// R11: R6's compute structure with the LDS/DMA/barriers deleted.
// Evidence trail:
//  - R6 (114.7us, 2.07 TB/s): vmcnt(0)+barrier drain of 52KB cold-HBM
//    weights convoys all waves at block start; in-flight bytes ~3KB/CU vs
//    ~9KB needed.
//  - R7/R9: hiding that drain via launch-bounds clamp / producer waves ->
//    register spills (WRITE 1.45GB / 0.45GB vs 24MB output).
//  - R10 (151us): no-LDS with register-resident h[13] -> allocator SANK the
//    read-only array (VGPR=48 < 52 needed), re-reading hori per iteration;
//    latency exposed 13x/row.
//  - Consolidated rule: ACCUMULATORS are the only values the allocator
//    never sinks. R6's tmp[4][13] survived at full size in every round.
// Structure: tmp[4][13] accumulation (un-sinkable), depth-1 img rotation
// (proven in R5/R6), depth-2 vert rotation streamed from global, hori
// loaded directly from global only in the epilogue (13 independent
// coalesced float4 loads). 3 channel-waves read identical weight addresses
// -> L1/L2 broadcast, no extra HBM traffic (don't stage what cache-fits).
// No sync point anywhere: outstanding bytes come from ~15 waves/CU
// continuously issuing, not from a drain-then-compute burst.

#define KK 13
#define NB 8
#define NC 3
#define IW 512
#define IH 512
#define WO 500
#define HO 500
#define QROW 125              // float4 quads per 500-col row
#define TJX 64                // j-quads per block
#define NT (TJX * NC)         // 192 threads = 3 waves

__global__ __launch_bounds__(NT) void sepconv_kernel(
    const float* __restrict__ img,
    const float* __restrict__ hori,
    const float* __restrict__ vert,
    float* __restrict__ out)
{
    const int tj = blockIdx.x * TJX + threadIdx.x;   // j-quad 0..127
    const int c  = threadIdx.y;                      // channel
    const int i  = blockIdx.y;                       // output row
    const int b  = blockIdx.z;                       // batch

    if (tj >= QROW) return;                          // tail lanes of group 1
    const int j0 = tj * 4;

    const size_t khw = (size_t)WO * HO;              // 250000
    const size_t rs4 = khw / 4;                      // 62500 float4 between k-slices

    const float4* hb = (const float4*)(hori + (size_t)b * KK * khw + (size_t)i * HO) + tj;
    const float4* vb = (const float4*)(vert + (size_t)b * KK * khw + (size_t)i * HO) + tj;
    const float*  ibase = img + (((size_t)(b * NC + c) * IW) + i) * IH + j0;

    float tmp[4][KK];
    #pragma unroll
    for (int jq = 0; jq < 4; ++jq)
        #pragma unroll
        for (int v = 0; v < KK; ++v)
            tmp[jq][v] = 0.0f;

    // ---- prologue: img row u=0, vert rows u=0,1 ----
    float4 vt_c = vb[0];
    float4 vt_n = vb[rs4];
    float4 c0 = *(const float4*)(ibase + 0);
    float4 c1 = *(const float4*)(ibase + 4);
    float4 c2 = *(const float4*)(ibase + 8);
    float4 c3 = *(const float4*)(ibase + 12);

    #pragma unroll
    for (int u = 0; u < KK; ++u) {
        // issue next img row + vert row u+2 before this iteration's FMAs
        float4 n0, n1, n2, n3, vt_nn;
        if (u < KK - 1) {
            const float* rp = ibase + (size_t)(u + 1) * IH;
            n0 = *(const float4*)(rp + 0);
            n1 = *(const float4*)(rp + 4);
            n2 = *(const float4*)(rp + 8);
            n3 = *(const float4*)(rp + 12);
        }
        if (u < KK - 2) {
            vt_nn = vb[(size_t)(u + 2) * rs4];
        }

        float row[16];
        row[0]  = c0.x; row[1]  = c0.y; row[2]  = c0.z; row[3]  = c0.w;
        row[4]  = c1.x; row[5]  = c1.y; row[6]  = c1.z; row[7]  = c1.w;
        row[8]  = c2.x; row[9]  = c2.y; row[10] = c2.z; row[11] = c2.w;
        row[12] = c3.x; row[13] = c3.y; row[14] = c3.z; row[15] = c3.w;

        #pragma unroll
        for (int v = 0; v < KK; ++v) {
            tmp[0][v] += row[0 + v] * vt_c.x;
            tmp[1][v] += row[1 + v] * vt_c.y;
            tmp[2][v] += row[2 + v] * vt_c.z;
            tmp[3][v] += row[3 + v] * vt_c.w;
        }

        if (u < KK - 1) {
            c0 = n0; c1 = n1; c2 = n2; c3 = n3;
        }
        vt_c = vt_n;
        vt_n = vt_nn;
    }

    // ---- epilogue: fold hori straight from global (13 independent
    // coalesced float4 loads; compiler batches them, one latency wait,
    // once per thread -- hidden by other blocks' compute via TLP).
    float4 o = make_float4(0.f, 0.f, 0.f, 0.f);
    #pragma unroll
    for (int v = 0; v < KK; ++v) {
        const float4 hv = hb[(size_t)v * rs4];
        o.x += tmp[0][v] * hv.x;
        o.y += tmp[1][v] * hv.y;
        o.z += tmp[2][v] * hv.z;
        o.w += tmp[3][v] * hv.w;
    }

    float* op = out + (((size_t)(b * NC + c) * WO) + i) * HO + j0;
    *(float4*)op = o;
}

extern "C" void kernel_launch(void* const* d_in, const int* in_sizes, int n_in,
                              void* d_out, int out_size, void* d_ws, size_t ws_size,
                              hipStream_t stream) {
    const float* img  = (const float*)d_in[0];
    const float* hori = (const float*)d_in[1];
    const float* vert = (const float*)d_in[2];
    float* out = (float*)d_out;

    dim3 block(TJX, NC, 1);       // x = j-quads, y = channel
    dim3 grid(2, WO, NB);         // x = quad-group, y = row i, z = batch
    hipLaunchKernelGGL(sepconv_kernel, grid, block, 0, stream, img, hori, vert, out);
}